// Round 12
// baseline (115.632 us; speedup 1.0000x reference)
//
#include <hip/hip_runtime.h>

#define NTOT   131072
#define GCNT   512
#define NGRP   256
#define KMARG  0.02f
#define CMARG  2.0f
#define EPSC   1e-6f

typedef float f4 __attribute__((ext_vector_type(4)));

// Multi-value block reduction: reduces M floats across the block (NW wave64s).
template <int NW, int M>
__device__ __forceinline__ void block_sum_m(float* v, float* red) {
  const int t = threadIdx.x;
#pragma unroll
  for (int m = 0; m < M; ++m) {
#pragma unroll
    for (int off = 32; off; off >>= 1) v[m] += __shfl_down(v[m], off, 64);
  }
  __syncthreads();
  if ((t & 63) == 0) {
#pragma unroll
    for (int m = 0; m < M; ++m) red[(t >> 6) * M + m] = v[m];
  }
  __syncthreads();
#pragma unroll
  for (int m = 0; m < M; ++m) {
    float s = 0.0f;
#pragma unroll
    for (int i = 0; i < NW; ++i) s += red[i * M + m];
    v[m] = s;
  }
}

__device__ __forceinline__ float wave_sum(float v) {
#pragma unroll
  for (int off = 32; off; off >>= 1) v += __shfl_down(v, off, 64);
  return v;
}

// R9 (112.7 us champion) + ONE change: wave-contiguous row ordering.
// Old: wave w reads rows {it*8 + 2w, +1} -> per-wave address train hops 16 KB
// every 2 rows; waves interleave at 4 KB granularity. New: wave w owns rows
// [w*64, w*64+64) and walks them sequentially -> one contiguous 128 KB run
// per stream per wave (better DRAM page locality, fewer open-page conflicts).
// Same work, same outputs, pure iteration-order permutation.
__global__ __launch_bounds__(256) void fused_kernel(const float* __restrict__ zr,
                                                    const float* __restrict__ zv,
                                                    const int* __restrict__ labels,
                                                    const int* __restrict__ varl,
                                                    float* __restrict__ dvec,
                                                    float* __restrict__ gout) {
  __shared__ float  red[4 * 4];
  __shared__ float  sd[NGRP];
  __shared__ float2 skv[NGRP];
  __shared__ float  sdat[NGRP];
  const int g = blockIdx.x, t = threadIdx.x;
  const int wave = t >> 6, lane = t & 63;

  // ---- Phase 1: dots. Wave w: rows w*64 .. w*64+63, 2 rows/iter, 32 iters ----
  const size_t rowbase = (size_t)g * NGRP;
#pragma unroll 2
  for (int it = 0; it < 32; ++it) {
    const int rg = wave * 64 + it * 2;           // wave-contiguous span
    const size_t row0 = rowbase + rg;
    const f4* r = (const f4*)zr + (row0 << 7);   // 128 f4 per row
    const f4* v = (const f4*)zv + (row0 << 7);
    f4 a0 = __builtin_nontemporal_load(r + lane);        // zr: NT (HBM stream)
    f4 b0 = v[lane];                                     // zv: cacheable (L3)
    f4 a1 = __builtin_nontemporal_load(r + lane + 64);
    f4 b1 = v[lane + 64];
    f4 a2 = __builtin_nontemporal_load(r + lane + 128);
    f4 b2 = v[lane + 128];
    f4 a3 = __builtin_nontemporal_load(r + lane + 192);
    f4 b3 = v[lane + 192];
    f4 p = a0 * b0 + a1 * b1;
    f4 q = a2 * b2 + a3 * b3;
    float s0 = wave_sum(p.x + p.y + p.z + p.w);
    float s1 = wave_sum(q.x + q.y + q.z + q.w);
    if (lane == 0) {
      const float d0 = 1.0f - s0, d1 = 1.0f - s1;
      sd[rg]     = d0;
      sd[rg + 1] = d1;
      dvec[row0]     = d0;
      dvec[row0 + 1] = d1;
    }
  }
  __syncthreads();

  // ---- Phase 2: group losses (all from LDS/registers; verbatim R3/R9) ----
  const int idx = g * NGRP + t;
  const float dv  = sd[t];
  const float vv  = (float)varl[idx];   // var_lens < 10000 -> exact in fp32
  const int   lab = labels[idx];

  skv[t] = make_float2(vv, dv);

  // A: sum d, sum v, label-0 d-sum, label-0 count
  float sA[4] = {dv, vv, (lab == 0) ? dv : 0.0f, (lab == 0) ? 1.0f : 0.0f};
  block_sum_m<4, 4>(sA, red);
  const float sumd = sA[0], sumv = sA[1], sb = sA[2], cb = sA[3];
  const float md = sumd * (1.0f / NGRP), mv = sumv * (1.0f / NGRP);

  // B: central moments (two-pass), corr loss in closed form
  const float vdev = vv - mv, ddev = dv - md;
  float sB[3] = {vdev * vdev, ddev * ddev, vdev * ddev};
  block_sum_m<4, 3>(sB, red);
  const float svv = sB[0], sdd = sB[1], svd = sB[2];
  const float vstd = sqrtf(svv * (1.0f / (NGRP - 1)));
  const float dstd = sqrtf(sdd * (1.0f / (NGRP - 1)));
  const float iv = 1.0f / (vstd + EPSC), id = 1.0f / (dstd + EPSC);
  float corr = (svv * iv * iv + sdd * id * id - 2.0f * svd * iv * id) * (1.0f / NGRP);
  corr = (vstd > 0.0f && dstd > 0.0f) ? corr : 0.0f;

  // C: pairwise rank loss (permutation-invariant) + stable rank for neighbor term
  int rank = 0;
  float pc = 0.0f, ps = 0.0f;
  const float pre = KMARG + dv;
  for (int j = 0; j < NGRP; ++j) {
    const float2 kv = skv[j];          // LDS broadcast
    const float vj = kv.x, dj = kv.y;
    if (vj > vv) {
      pc += 1.0f;
      ps += fmaxf(pre - dj, 0.0f);
    }
    rank += (vj < vv || (vj == vv && j < t)) ? 1 : 0;  // stable rank
  }
  sdat[rank] = dv;                     // scatter into sorted-by-v order
  __syncthreads();
  const float nv = (t < NGRP - 1) ? fmaxf(sdat[t] - sdat[t + 1] + KMARG, 0.0f) : 0.0f;

  float sC[3] = {ps, pc, nv};
  block_sum_m<4, 3>(sC, red);
  const float rank_loss = (sC[1] > 0.0f) ? sC[0] / fmaxf(sC[1], 1.0f) : 0.0f;
  const float neigh = sC[2] * (1.0f / (NGRP - 1));

  if (t == 0) {
    gout[g]            = corr + neigh + rank_loss;
    gout[GCNT + g]     = sb;
    gout[2 * GCNT + g] = cb;
    gout[3 * GCNT + g] = sumd;
  }
}

__global__ __launch_bounds__(512) void final_kernel(const float* __restrict__ gout,
                                                    float* __restrict__ out) {
  __shared__ float red[8 * 4];
  const int t = threadIdx.x;
  float s[4] = {gout[t], gout[GCNT + t], gout[2 * GCNT + t], gout[3 * GCNT + t]};
  block_sum_m<8, 4>(s, red);
  if (t == 0) {
    const float L = s[0], SB = s[1], CB = s[2], SumD = s[3];
    const float SP = SumD - SB;
    const float CP = (float)NTOT - CB;
    const float db = SB / fmaxf(CB, 1.0f);
    const float dp = SP / fmaxf(CP, 1.0f);
    const float l_cdd = (CB > 0.0f && CP > 0.0f) ? fmaxf(CMARG + db - dp, 0.0f) : 0.0f;
    const float l_pcc = L * (1.0f / GCNT);
    out[0] = l_cdd + l_pcc;   // LAMBDA_CD = 0
    out[1] = l_cdd;
    out[2] = l_pcc;
  }
}

extern "C" void kernel_launch(void* const* d_in, const int* in_sizes, int n_in,
                              void* d_out, int out_size, void* d_ws, size_t ws_size,
                              hipStream_t stream) {
  const float* zr     = (const float*)d_in[0];
  const float* zv     = (const float*)d_in[1];
  const int*   labels = (const int*)d_in[2];
  // d_in[3] = groups: contiguous equal-size -> derivable, unused
  const int*   varl   = (const int*)d_in[4];
  float* out  = (float*)d_out;
  float* dvec = out + 3;          // out[3..] = d (N floats)
  float* gws  = (float*)d_ws;     // G*4 floats of group partials

  fused_kernel<<<GCNT, 256, 0, stream>>>(zr, zv, labels, varl, dvec, gws);
  final_kernel<<<1, 512, 0, stream>>>(gws, out);
}

// Round 13
// 114.250 us; speedup vs baseline: 1.0121x; 1.0121x over previous
//
#include <hip/hip_runtime.h>

#define NTOT   131072
#define GCNT   512
#define NGRP   256
#define KMARG  0.02f
#define CMARG  2.0f
#define EPSC   1e-6f

typedef float f4 __attribute__((ext_vector_type(4)));

// Forced-MLP loads: inline asm the compiler cannot sink/collapse. One base
// address per stream per row-pair; 4 KB covered via offset: immediates.
// zr: nt (no L3 retention). zv: cacheable (L3-resident across replays, R9).
#define GLD4_NT(d0, d1, d2, d3, p)                                         \
  asm volatile("global_load_dwordx4 %0, %4, off nt\n\t"                    \
               "global_load_dwordx4 %1, %4, off offset:1024 nt\n\t"        \
               "global_load_dwordx4 %2, %4, off offset:2048 nt\n\t"        \
               "global_load_dwordx4 %3, %4, off offset:3072 nt"            \
               : "=&v"(d0), "=&v"(d1), "=&v"(d2), "=&v"(d3) : "v"(p))
#define GLD4_CA(d0, d1, d2, d3, p)                                         \
  asm volatile("global_load_dwordx4 %0, %4, off\n\t"                       \
               "global_load_dwordx4 %1, %4, off offset:1024\n\t"           \
               "global_load_dwordx4 %2, %4, off offset:2048\n\t"           \
               "global_load_dwordx4 %3, %4, off offset:3072"               \
               : "=&v"(d0), "=&v"(d1), "=&v"(d2), "=&v"(d3) : "v"(p))
// Counted waits; sched_barrier(0) per guide rule #18 (hipcc hoists past
// inline-asm waitcnt otherwise).
#define WAIT8 do { asm volatile("s_waitcnt vmcnt(8)" ::: "memory");        \
                   __builtin_amdgcn_sched_barrier(0); } while (0)
#define WAIT0 do { asm volatile("s_waitcnt vmcnt(0)" ::: "memory");        \
                   __builtin_amdgcn_sched_barrier(0); } while (0)

// Multi-value block reduction: reduces M floats across the block (NW wave64s).
template <int NW, int M>
__device__ __forceinline__ void block_sum_m(float* v, float* red) {
  const int t = threadIdx.x;
#pragma unroll
  for (int m = 0; m < M; ++m) {
#pragma unroll
    for (int off = 32; off; off >>= 1) v[m] += __shfl_down(v[m], off, 64);
  }
  __syncthreads();
  if ((t & 63) == 0) {
#pragma unroll
    for (int m = 0; m < M; ++m) red[(t >> 6) * M + m] = v[m];
  }
  __syncthreads();
#pragma unroll
  for (int m = 0; m < M; ++m) {
    float s = 0.0f;
#pragma unroll
    for (int i = 0; i < NW; ++i) s += red[i * M + m];
    v[m] = s;
  }
}

__device__ __forceinline__ float wave_sum(float v) {
#pragma unroll
  for (int off = 32; off; off >>= 1) v += __shfl_down(v, off, 64);
  return v;
}

// R9 champion + forced 8 KB/wave MLP: ping-pong asm register sets, counted
// vmcnt(8) (never 0 mid-loop). Every VGPR-load variant so far collapsed to
// ~2 loads in flight (VGPR=28); Little's law then caps reads at ~4.9 TB/s,
// matching all measurements. Asm outputs force the allocator to hold 64 data
// VGPRs; the next stage's 8 loads fly while the current stage is consumed.
__global__ __launch_bounds__(256) void fused_kernel(const float* __restrict__ zr,
                                                    const float* __restrict__ zv,
                                                    const int* __restrict__ labels,
                                                    const int* __restrict__ varl,
                                                    float* __restrict__ dvec,
                                                    float* __restrict__ gout) {
  __shared__ float  red[4 * 4];
  __shared__ float  sd[NGRP];
  __shared__ float2 skv[NGRP];
  __shared__ float  sdat[NGRP];
  const int g = blockIdx.x, t = threadIdx.x;
  const int wave = t >> 6, lane = t & 63;
  const size_t rowbase = (size_t)g * NGRP;
  const f4* zr4 = (const f4*)zr;
  const f4* zv4 = (const f4*)zv;

#define ISSUE(k, R0, R1, R2, R3, V0, V1, V2, V3) do {                      \
    const size_t row0_ = rowbase + (size_t)((k) * 8 + wave * 2);           \
    const f4* pr_ = zr4 + (row0_ << 7) + lane;                             \
    const f4* pv_ = zv4 + (row0_ << 7) + lane;                             \
    GLD4_NT(R0, R1, R2, R3, pr_);                                          \
    GLD4_CA(V0, V1, V2, V3, pv_);                                          \
  } while (0)

#define CONSUME(k, R0, R1, R2, R3, V0, V1, V2, V3) do {                    \
    f4 p_ = R0 * V0 + R1 * V1;                                             \
    f4 q_ = R2 * V2 + R3 * V3;                                             \
    float s0_ = wave_sum((p_.x + p_.y) + (p_.z + p_.w));                   \
    float s1_ = wave_sum((q_.x + q_.y) + (q_.z + q_.w));                   \
    const int rg_ = (k) * 8 + wave * 2;                                    \
    if (lane == 0) {                                                       \
      sd[rg_]     = 1.0f - s0_;                                            \
      sd[rg_ + 1] = 1.0f - s1_;                                            \
    }                                                                      \
  } while (0)

  f4 Ra0, Ra1, Ra2, Ra3, Va0, Va1, Va2, Va3;   // stage A (8 f4 = 32 VGPR)
  f4 Rb0, Rb1, Rb2, Rb3, Vb0, Vb1, Vb2, Vb3;   // stage B

  ISSUE(0, Ra0, Ra1, Ra2, Ra3, Va0, Va1, Va2, Va3);
#pragma unroll 1
  for (int kk = 0; kk < 15; ++kk) {
    const int k = 2 * kk;
    ISSUE(k + 1, Rb0, Rb1, Rb2, Rb3, Vb0, Vb1, Vb2, Vb3);  // 8 in flight over A
    WAIT8;                                                  // A complete
    CONSUME(k, Ra0, Ra1, Ra2, Ra3, Va0, Va1, Va2, Va3);
    ISSUE(k + 2, Ra0, Ra1, Ra2, Ra3, Va0, Va1, Va2, Va3);  // 8 in flight over B
    WAIT8;                                                  // B complete
    CONSUME(k + 1, Rb0, Rb1, Rb2, Rb3, Vb0, Vb1, Vb2, Vb3);
  }
  ISSUE(31, Rb0, Rb1, Rb2, Rb3, Vb0, Vb1, Vb2, Vb3);
  WAIT8;
  CONSUME(30, Ra0, Ra1, Ra2, Ra3, Va0, Va1, Va2, Va3);
  WAIT0;
  CONSUME(31, Rb0, Rb1, Rb2, Rb3, Vb0, Vb1, Vb2, Vb3);
#undef ISSUE
#undef CONSUME
  __syncthreads();

  // Coalesced d output (1 KB contiguous per block); NT store (write-only).
  __builtin_nontemporal_store(sd[t], dvec + rowbase + t);

  // ---- Phase 2: group losses (all from LDS/registers; verbatim R3/R9) ----
  const int idx = g * NGRP + t;
  const float dv  = sd[t];
  const float vv  = (float)varl[idx];   // var_lens < 10000 -> exact in fp32
  const int   lab = labels[idx];

  skv[t] = make_float2(vv, dv);

  // A: sum d, sum v, label-0 d-sum, label-0 count
  float sA[4] = {dv, vv, (lab == 0) ? dv : 0.0f, (lab == 0) ? 1.0f : 0.0f};
  block_sum_m<4, 4>(sA, red);
  const float sumd = sA[0], sumv = sA[1], sb = sA[2], cb = sA[3];
  const float md = sumd * (1.0f / NGRP), mv = sumv * (1.0f / NGRP);

  // B: central moments (two-pass), corr loss in closed form
  const float vdev = vv - mv, ddev = dv - md;
  float sB[3] = {vdev * vdev, ddev * ddev, vdev * ddev};
  block_sum_m<4, 3>(sB, red);
  const float svv = sB[0], sdd = sB[1], svd = sB[2];
  const float vstd = sqrtf(svv * (1.0f / (NGRP - 1)));
  const float dstd = sqrtf(sdd * (1.0f / (NGRP - 1)));
  const float iv = 1.0f / (vstd + EPSC), id = 1.0f / (dstd + EPSC);
  float corr = (svv * iv * iv + sdd * id * id - 2.0f * svd * iv * id) * (1.0f / NGRP);
  corr = (vstd > 0.0f && dstd > 0.0f) ? corr : 0.0f;

  // C: pairwise rank loss (permutation-invariant) + stable rank for neighbor term
  int rank = 0;
  float pc = 0.0f, ps = 0.0f;
  const float pre = KMARG + dv;
  for (int j = 0; j < NGRP; ++j) {
    const float2 kv = skv[j];          // LDS broadcast
    const float vj = kv.x, dj = kv.y;
    if (vj > vv) {
      pc += 1.0f;
      ps += fmaxf(pre - dj, 0.0f);
    }
    rank += (vj < vv || (vj == vv && j < t)) ? 1 : 0;  // stable rank
  }
  sdat[rank] = dv;                     // scatter into sorted-by-v order
  __syncthreads();
  const float nv = (t < NGRP - 1) ? fmaxf(sdat[t] - sdat[t + 1] + KMARG, 0.0f) : 0.0f;

  float sC[3] = {ps, pc, nv};
  block_sum_m<4, 3>(sC, red);
  const float rank_loss = (sC[1] > 0.0f) ? sC[0] / fmaxf(sC[1], 1.0f) : 0.0f;
  const float neigh = sC[2] * (1.0f / (NGRP - 1));

  if (t == 0) {
    gout[g]            = corr + neigh + rank_loss;
    gout[GCNT + g]     = sb;
    gout[2 * GCNT + g] = cb;
    gout[3 * GCNT + g] = sumd;
  }
}

__global__ __launch_bounds__(512) void final_kernel(const float* __restrict__ gout,
                                                    float* __restrict__ out) {
  __shared__ float red[8 * 4];
  const int t = threadIdx.x;
  float s[4] = {gout[t], gout[GCNT + t], gout[2 * GCNT + t], gout[3 * GCNT + t]};
  block_sum_m<8, 4>(s, red);
  if (t == 0) {
    const float L = s[0], SB = s[1], CB = s[2], SumD = s[3];
    const float SP = SumD - SB;
    const float CP = (float)NTOT - CB;
    const float db = SB / fmaxf(CB, 1.0f);
    const float dp = SP / fmaxf(CP, 1.0f);
    const float l_cdd = (CB > 0.0f && CP > 0.0f) ? fmaxf(CMARG + db - dp, 0.0f) : 0.0f;
    const float l_pcc = L * (1.0f / GCNT);
    out[0] = l_cdd + l_pcc;   // LAMBDA_CD = 0
    out[1] = l_cdd;
    out[2] = l_pcc;
  }
}

extern "C" void kernel_launch(void* const* d_in, const int* in_sizes, int n_in,
                              void* d_out, int out_size, void* d_ws, size_t ws_size,
                              hipStream_t stream) {
  const float* zr     = (const float*)d_in[0];
  const float* zv     = (const float*)d_in[1];
  const int*   labels = (const int*)d_in[2];
  // d_in[3] = groups: contiguous equal-size -> derivable, unused
  const int*   varl   = (const int*)d_in[4];
  float* out  = (float*)d_out;
  float* dvec = out + 3;          // out[3..] = d (N floats)
  float* gws  = (float*)d_ws;     // G*4 floats of group partials

  fused_kernel<<<GCNT, 256, 0, stream>>>(zr, zv, labels, varl, dvec, gws);
  final_kernel<<<1, 512, 0, stream>>>(gws, out);
}

// Round 14
// 112.286 us; speedup vs baseline: 1.0298x; 1.0175x over previous
//
#include <hip/hip_runtime.h>

#define NTOT   131072
#define GCNT   512
#define NGRP   256
#define KMARG  0.02f
#define CMARG  2.0f
#define EPSC   1e-6f

typedef float f4 __attribute__((ext_vector_type(4)));

// Forced-issue loads (asm: compiler cannot sink/reorder them).
// zr: nt (no L3 retention). zv: cacheable (L3-resident across replays).
#define GLD4_NT(d0, d1, d2, d3, p)                                         \
  asm volatile("global_load_dwordx4 %0, %4, off nt\n\t"                    \
               "global_load_dwordx4 %1, %4, off offset:1024 nt\n\t"        \
               "global_load_dwordx4 %2, %4, off offset:2048 nt\n\t"        \
               "global_load_dwordx4 %3, %4, off offset:3072 nt"            \
               : "=&v"(d0), "=&v"(d1), "=&v"(d2), "=&v"(d3) : "v"(p))
#define GLD4_CA(d0, d1, d2, d3, p)                                         \
  asm volatile("global_load_dwordx4 %0, %4, off\n\t"                       \
               "global_load_dwordx4 %1, %4, off offset:1024\n\t"           \
               "global_load_dwordx4 %2, %4, off offset:2048\n\t"           \
               "global_load_dwordx4 %3, %4, off offset:3072"               \
               : "=&v"(d0), "=&v"(d1), "=&v"(d2), "=&v"(d3) : "v"(p))
// Counted waits + sched_barrier(0) fence (guide rule #18).
#define WAITN(n) do { asm volatile("s_waitcnt vmcnt(" #n ")" ::: "memory"); \
                      __builtin_amdgcn_sched_barrier(0); } while (0)

template <int NW, int M>
__device__ __forceinline__ void block_sum_m(float* v, float* red) {
  const int t = threadIdx.x;
#pragma unroll
  for (int m = 0; m < M; ++m) {
#pragma unroll
    for (int off = 32; off; off >>= 1) v[m] += __shfl_down(v[m], off, 64);
  }
  __syncthreads();
  if ((t & 63) == 0) {
#pragma unroll
    for (int m = 0; m < M; ++m) red[(t >> 6) * M + m] = v[m];
  }
  __syncthreads();
#pragma unroll
  for (int m = 0; m < M; ++m) {
    float s = 0.0f;
#pragma unroll
    for (int i = 0; i < NW; ++i) s += red[i * M + m];
    v[m] = s;
  }
}

__device__ __forceinline__ float wave_sum(float v) {
#pragma unroll
  for (int off = 32; off; off >>= 1) v += __shfl_down(v, off, 64);
  return v;
}

// Champion structure + STREAM SKEW: zr and zv bases differ by exactly 2^28,
// so paired zr[row]/zv[row] requests share a channel phase; zipped issue sends
// both to the SAME channel at the same instant, halving effective channel
// parallelism. Fix: pipeline the V stream one 4 KB stage ahead of R --
// simultaneous cohorts are R(k+1) and V(k+2), 16 KB apart -> different
// channel granules. 3-deep V rotation, 2-deep R, counted vmcnt(12).
__global__ __launch_bounds__(256) void fused_kernel(const float* __restrict__ zr,
                                                    const float* __restrict__ zv,
                                                    const int* __restrict__ labels,
                                                    const int* __restrict__ varl,
                                                    float* __restrict__ dvec,
                                                    float* __restrict__ gout) {
  __shared__ float  red[4 * 4];
  __shared__ float  sd[NGRP];
  __shared__ float2 skv[NGRP];
  __shared__ float  sdat[NGRP];
  const int g = blockIdx.x, t = threadIdx.x;
  const int wave = t >> 6, lane = t & 63;
  const size_t rowbase = (size_t)g * NGRP;
  const f4* zr4 = (const f4*)zr;
  const f4* zv4 = (const f4*)zv;

#define ISSUE_R(k, S0, S1, S2, S3) do {                                    \
    const f4* pr_ = zr4 + ((rowbase + (size_t)((k) * 8 + wave * 2)) << 7) + lane; \
    GLD4_NT(S0, S1, S2, S3, pr_);                                          \
  } while (0)
#define ISSUE_V(k, S0, S1, S2, S3) do {                                    \
    const f4* pv_ = zv4 + ((rowbase + (size_t)((k) * 8 + wave * 2)) << 7) + lane; \
    GLD4_CA(S0, S1, S2, S3, pv_);                                          \
  } while (0)
#define CONSUME(k, R0, R1, R2, R3, V0, V1, V2, V3) do {                    \
    f4 p_ = R0 * V0 + R1 * V1;                                             \
    f4 q_ = R2 * V2 + R3 * V3;                                             \
    float s0_ = wave_sum((p_.x + p_.y) + (p_.z + p_.w));                   \
    float s1_ = wave_sum((q_.x + q_.y) + (q_.z + q_.w));                   \
    const int rg_ = (k) * 8 + wave * 2;                                    \
    if (lane == 0) {                                                       \
      sd[rg_]     = 1.0f - s0_;                                            \
      sd[rg_ + 1] = 1.0f - s1_;                                            \
    }                                                                      \
  } while (0)

  f4 Ra0, Ra1, Ra2, Ra3, Rb0, Rb1, Rb2, Rb3, Rc0, Rc1, Rc2, Rc3;
  f4 Va0, Va1, Va2, Va3, Vb0, Vb1, Vb2, Vb3, Vc0, Vc1, Vc2, Vc3;

  // Prologue: V leads R by one stage from the first request.
  ISSUE_V(0, Va0, Va1, Va2, Va3);
  ISSUE_R(0, Ra0, Ra1, Ra2, Ra3);
  ISSUE_V(1, Vb0, Vb1, Vb2, Vb3);
#pragma unroll 1
  for (int kk = 0; kk < 10; ++kk) {
    const int k = 3 * kk;
    ISSUE_R(k + 1, Rb0, Rb1, Rb2, Rb3);
    ISSUE_V(k + 2, Vc0, Vc1, Vc2, Vc3);
    WAITN(12);
    CONSUME(k, Ra0, Ra1, Ra2, Ra3, Va0, Va1, Va2, Va3);
    ISSUE_R(k + 2, Rc0, Rc1, Rc2, Rc3);
    ISSUE_V(k + 3, Va0, Va1, Va2, Va3);
    WAITN(12);
    CONSUME(k + 1, Rb0, Rb1, Rb2, Rb3, Vb0, Vb1, Vb2, Vb3);
    ISSUE_R(k + 3, Ra0, Ra1, Ra2, Ra3);
    ISSUE_V(k + 4, Vb0, Vb1, Vb2, Vb3);
    WAITN(12);
    CONSUME(k + 2, Rc0, Rc1, Rc2, Rc3, Vc0, Vc1, Vc2, Vc3);
  }
  // Loop exit state: Ra=R30, Va=V30, Vb=V31 in flight (12 outstanding).
  ISSUE_R(31, Rb0, Rb1, Rb2, Rb3);
  WAITN(8);
  CONSUME(30, Ra0, Ra1, Ra2, Ra3, Va0, Va1, Va2, Va3);
  WAITN(0);
  CONSUME(31, Rb0, Rb1, Rb2, Rb3, Vb0, Vb1, Vb2, Vb3);
#undef ISSUE_R
#undef ISSUE_V
#undef CONSUME
  __syncthreads();

  // Coalesced d output (1 KB contiguous per block); NT store (write-only).
  __builtin_nontemporal_store(sd[t], dvec + rowbase + t);

  // ---- Phase 2: group losses (all from LDS/registers; verbatim champion) ----
  const int idx = g * NGRP + t;
  const float dv  = sd[t];
  const float vv  = (float)varl[idx];   // var_lens < 10000 -> exact in fp32
  const int   lab = labels[idx];

  skv[t] = make_float2(vv, dv);

  float sA[4] = {dv, vv, (lab == 0) ? dv : 0.0f, (lab == 0) ? 1.0f : 0.0f};
  block_sum_m<4, 4>(sA, red);
  const float sumd = sA[0], sumv = sA[1], sb = sA[2], cb = sA[3];
  const float md = sumd * (1.0f / NGRP), mv = sumv * (1.0f / NGRP);

  const float vdev = vv - mv, ddev = dv - md;
  float sB[3] = {vdev * vdev, ddev * ddev, vdev * ddev};
  block_sum_m<4, 3>(sB, red);
  const float svv = sB[0], sdd = sB[1], svd = sB[2];
  const float vstd = sqrtf(svv * (1.0f / (NGRP - 1)));
  const float dstd = sqrtf(sdd * (1.0f / (NGRP - 1)));
  const float iv = 1.0f / (vstd + EPSC), id = 1.0f / (dstd + EPSC);
  float corr = (svv * iv * iv + sdd * id * id - 2.0f * svd * iv * id) * (1.0f / NGRP);
  corr = (vstd > 0.0f && dstd > 0.0f) ? corr : 0.0f;

  int rank = 0;
  float pc = 0.0f, ps = 0.0f;
  const float pre = KMARG + dv;
  for (int j = 0; j < NGRP; ++j) {
    const float2 kv = skv[j];          // LDS broadcast
    const float vj = kv.x, dj = kv.y;
    if (vj > vv) {
      pc += 1.0f;
      ps += fmaxf(pre - dj, 0.0f);
    }
    rank += (vj < vv || (vj == vv && j < t)) ? 1 : 0;  // stable rank
  }
  sdat[rank] = dv;                     // scatter into sorted-by-v order
  __syncthreads();
  const float nv = (t < NGRP - 1) ? fmaxf(sdat[t] - sdat[t + 1] + KMARG, 0.0f) : 0.0f;

  float sC[3] = {ps, pc, nv};
  block_sum_m<4, 3>(sC, red);
  const float rank_loss = (sC[1] > 0.0f) ? sC[0] / fmaxf(sC[1], 1.0f) : 0.0f;
  const float neigh = sC[2] * (1.0f / (NGRP - 1));

  if (t == 0) {
    gout[g]            = corr + neigh + rank_loss;
    gout[GCNT + g]     = sb;
    gout[2 * GCNT + g] = cb;
    gout[3 * GCNT + g] = sumd;
  }
}

__global__ __launch_bounds__(512) void final_kernel(const float* __restrict__ gout,
                                                    float* __restrict__ out) {
  __shared__ float red[8 * 4];
  const int t = threadIdx.x;
  float s[4] = {gout[t], gout[GCNT + t], gout[2 * GCNT + t], gout[3 * GCNT + t]};
  block_sum_m<8, 4>(s, red);
  if (t == 0) {
    const float L = s[0], SB = s[1], CB = s[2], SumD = s[3];
    const float SP = SumD - SB;
    const float CP = (float)NTOT - CB;
    const float db = SB / fmaxf(CB, 1.0f);
    const float dp = SP / fmaxf(CP, 1.0f);
    const float l_cdd = (CB > 0.0f && CP > 0.0f) ? fmaxf(CMARG + db - dp, 0.0f) : 0.0f;
    const float l_pcc = L * (1.0f / GCNT);
    out[0] = l_cdd + l_pcc;   // LAMBDA_CD = 0
    out[1] = l_cdd;
    out[2] = l_pcc;
  }
}

extern "C" void kernel_launch(void* const* d_in, const int* in_sizes, int n_in,
                              void* d_out, int out_size, void* d_ws, size_t ws_size,
                              hipStream_t stream) {
  const float* zr     = (const float*)d_in[0];
  const float* zv     = (const float*)d_in[1];
  const int*   labels = (const int*)d_in[2];
  // d_in[3] = groups: contiguous equal-size -> derivable, unused
  const int*   varl   = (const int*)d_in[4];
  float* out  = (float*)d_out;
  float* dvec = out + 3;          // out[3..] = d (N floats)
  float* gws  = (float*)d_ws;     // G*4 floats of group partials

  fused_kernel<<<GCNT, 256, 0, stream>>>(zr, zv, labels, varl, dvec, gws);
  final_kernel<<<1, 512, 0, stream>>>(gws, out);
}